// Round 6
// baseline (240.311 us; speedup 1.0000x reference)
//
#include <hip/hip_runtime.h>
#include <math.h>

// Problem constants (x: [8192, 512] fp32, K=5, eps=1e-8, scalar fp32 loss)
#define NROWS 8192
#define DIM   512
#define KNN   5
#define EPSV  1e-8f

// GEMM tiling: 128x128 block tile, 4 waves (2x2), each wave 4x4 of 16x16x32
// MFMA. Round-6: NO LDS AT ALL in the dots kernel — fragments are loaded
// directly from global (L2-resident panels). Intra-block staging reuse was
// only 2x per operand, so direct loads move the SAME bytes from L2 while
// removing every barrier / vmcnt(0) drain (the diagnosed serializer; r1/r3/r5
// all failed to hide it with TLP or deeper tiles). L1 absorbs the 2x dup.
#define BM 128
#define BN 128
#define BK 32
#define NT (NROWS / BM)        // 64 tile indices per dimension
#define NT64 (NROWS / 64)      // 128 64-col tiles per row
#define NKS (DIM / BK)         // 16 K-steps
#define NWORK 2080             // 64*65/2 upper-triangular work blocks (= 8*260)
#define NSEL (NROWS / 4)       // select blocks (4 waves, 1 row/wave) = 2048

typedef __attribute__((ext_vector_type(8))) _Float16 f16x8;
typedef __attribute__((ext_vector_type(4))) float    f32x4;

__device__ __forceinline__ void cmpswap(float& a, float& b) {
    const float hi = fmaxf(a, b), lo = fminf(a, b);
    a = hi; b = lo;
}

// merge two sorted-descending 5-lists -> top-5 (into a).
__device__ __forceinline__ void merge5(float a[KNN], const float b[KNN]) {
    const float c0 = fmaxf(a[0], b[0]);
    const float c1 = fmaxf(fmaxf(a[1], b[1]), fminf(a[0], b[0]));
    const float c2 = fmaxf(fmaxf(a[2], b[2]),
                           fmaxf(fminf(a[0], b[1]), fminf(a[1], b[0])));
    const float c3 = fmaxf(fmaxf(a[3], b[3]),
                           fmaxf(fminf(a[0], b[2]),
                                 fmaxf(fminf(a[1], b[1]), fminf(a[2], b[0]))));
    const float c4 = fmaxf(fmaxf(a[4], b[4]),
                           fmaxf(fmaxf(fminf(a[0], b[3]), fminf(a[1], b[2])),
                                 fmaxf(fminf(a[2], b[1]), fminf(a[3], b[0]))));
    a[0] = c0; a[1] = c1; a[2] = c2; a[3] = c3; a[4] = c4;
}

// ---------------------------------------------------------------------------
// Kernel 1: row-normalize x (fp32) -> xn (f16). One WAVE per row, 16B stores.
// ---------------------------------------------------------------------------
__global__ __launch_bounds__(256) void norm_kernel(const float* __restrict__ x,
                                                   _Float16* __restrict__ xnh) {
    const int wv = threadIdx.x >> 6, lane = threadIdx.x & 63;
    const int row = blockIdx.x * 4 + wv;
    const float4* xr = (const float4*)(x + (size_t)row * DIM) + lane * 2;
    const float4 a = xr[0];
    const float4 b = xr[1];
    float s = a.x * a.x + a.y * a.y + a.z * a.z + a.w * a.w
            + b.x * b.x + b.y * b.y + b.z * b.z + b.w * b.w;
    #pragma unroll
    for (int off = 1; off < 64; off <<= 1) s += __shfl_xor(s, off, 64);
    const float inv = 1.0f / sqrtf(s);
    const f16x8 h = { (_Float16)(a.x * inv), (_Float16)(a.y * inv),
                      (_Float16)(a.z * inv), (_Float16)(a.w * inv),
                      (_Float16)(b.x * inv), (_Float16)(b.y * inv),
                      (_Float16)(b.z * inv), (_Float16)(b.w * inv) };
    *(f16x8*)(xnh + (size_t)row * DIM + lane * 8) = h;
}

// ---------------------------------------------------------------------------
// Kernel 2: TRIANGULAR Gram-tile GEMM + per-(row, 64-col-tile) top-3.
// Round-6: barrier-free direct-from-global fragment loads (no LDS).
//  - Fragment addresses reproduce the old LDS fragment layout exactly
//    (row = tile_base + sub*16 + m_lane, bytes k0 + quad*8), so MFMA
//    operands are bit-identical to the verified r4 kernel.
//  - Per wave-fragment load the wave touches 16 rows x 64 B contiguous —
//    16 L2 lines, same lines the staging loop fetched.
//  - No __syncthreads in the kernel: waves pipeline loads across K-steps
//    freely; the per-K-step vmcnt(0) drain (r1/r3/r5's immovable stall)
//    is gone structurally.
//  - XCD super-tile schedule KEPT (r2: FETCH 33->23MB, -16us): keeps the
//    panel working set (2MB per 8x8 super-tile) resident in each XCD L2.
// ---------------------------------------------------------------------------
__global__ __launch_bounds__(256) void dots_top3_kernel(const _Float16* __restrict__ xnh,
                                                        float* __restrict__ M3) {
    // ---- work-index decode: launch b -> XCD-contiguous work item w -> (I,J)
    // XCD x = b&7 gets slots w in [x*260, (x+1)*260); work enumerated over
    // super-tiles (SI,SJ>=SI) of 8x8 tiles; diag super-tiles hold the 36
    // upper-tri pairs, off-diag hold all 64. Totals: 8*36 + 28*64 = 2080.
    int I, J;
    {
        int rem = (int)(blockIdx.x & 7) * (NWORK / 8) + (int)(blockIdx.x >> 3);
        int found = 0;
        for (int SI = 0; SI < 8 && !found; ++SI) {
            for (int SJ = SI; SJ < 8 && !found; ++SJ) {
                const int sz = (SI == SJ) ? 36 : 64;
                if (rem < sz) {
                    if (SI == SJ) {
                        int i = 0, r2 = rem;
                        while (r2 >= 8 - i) { r2 -= 8 - i; ++i; }
                        I = SI * 8 + i;
                        J = SJ * 8 + i + r2;
                    } else {
                        I = SI * 8 + (rem >> 3);
                        J = SJ * 8 + (rem & 7);
                    }
                    found = 1;
                } else {
                    rem -= sz;
                }
            }
        }
    }

    const int tid    = threadIdx.x;
    const int lane   = tid & 63;
    const int wv     = tid >> 6;
    const int wm     = wv >> 1;          // wave row half (0..1)
    const int wn     = wv & 1;           // wave col half (0..1)
    const int m_lane = lane & 15;        // MFMA: m (A) / n (B) / col (C)
    const int quad   = lane >> 4;        // MFMA: k-chunk (A,B) / row-group (C)

    const int i0 = I * BM;
    const int j0 = J * BN;

    // lane (quad, m_lane) owns row rowlocal (its (m,i) = (m_lane>>2, m_lane&3))
    const int rowlocal = (m_lane >> 2) * 16 + quad * 4 + (m_lane & 3);
    const int myrow    = i0 + wm * 64 + rowlocal;

    // per-lane fragment base pointers (identical data to the old LDS reads)
    const _Float16* pa = xnh + (size_t)(i0 + wm * 64 + m_lane) * DIM + quad * 8;
    const _Float16* pb = xnh + (size_t)(j0 + wn * 64 + m_lane) * DIM + quad * 8;

    f32x4 acc[4][4];
    #pragma unroll
    for (int m = 0; m < 4; ++m)
        #pragma unroll
        for (int n = 0; n < 4; ++n)
            acc[m][n] = (f32x4){0.f, 0.f, 0.f, 0.f};

    #pragma unroll 4
    for (int ks = 0; ks < NKS; ++ks) {
        const int ko = ks * BK;
        f16x8 af[4], bf[4];
        #pragma unroll
        for (int m = 0; m < 4; ++m)
            af[m] = *(const f16x8*)(pa + (size_t)m * 16 * DIM + ko);
        #pragma unroll
        for (int n = 0; n < 4; ++n)
            bf[n] = *(const f16x8*)(pb + (size_t)n * 16 * DIM + ko);
        #pragma unroll
        for (int m = 0; m < 4; ++m)
            #pragma unroll
            for (int n = 0; n < 4; ++n)
                acc[m][n] = __builtin_amdgcn_mfma_f32_16x16x32_f16(af[m], bf[n], acc[m][n], 0, 0, 0);
    }

    // diagonal mask: self-dot only when I==J && wm==wn && m==n.
    const bool diag = (I == J) && (wm == wn);
    #pragma unroll
    for (int m = 0; m < 4; ++m)
        #pragma unroll
        for (int i = 0; i < 4; ++i)
            acc[m][m][i] = (diag && (quad * 4 + i) == m_lane) ? -2.f : acc[m][m][i];

    // ---- row-side: per (m,i), top-3 of this row's 64 cols (butterfly) ----
    float g1 = -2.f, g2 = -2.f, g3 = -2.f;
    #pragma unroll
    for (int m = 0; m < 4; ++m) {
        #pragma unroll
        for (int i = 0; i < 4; ++i) {
            float v0 = acc[m][0][i], v1 = acc[m][1][i];
            float v2 = acc[m][2][i], v3 = acc[m][3][i];
            cmpswap(v0, v1); cmpswap(v2, v3);
            cmpswap(v0, v2); cmpswap(v1, v3);
            cmpswap(v1, v2);                     // v0>=v1>=v2 (>=v3, dropped)
            float a1 = v0, a2 = v1, a3 = v2;
            #pragma unroll
            for (int d = 1; d < 16; d <<= 1) {
                const float b1 = __shfl_xor(a1, d, 64);
                const float b2 = __shfl_xor(a2, d, 64);
                const float b3 = __shfl_xor(a3, d, 64);
                const float n1 = fmaxf(a1, b1);
                const float n2 = fmaxf(fminf(a1, b1), fmaxf(a2, b2));
                const float n3 = fmaxf(fmaxf(a3, b3),
                                       fmaxf(fminf(a1, b2), fminf(a2, b1)));
                a1 = n1; a2 = n2; a3 = n3;
            }
            const bool own = (m_lane == m * 4 + i);
            g1 = own ? a1 : g1; g2 = own ? a2 : g2; g3 = own ? a3 : g3;
        }
    }
    {
        float* p = M3 + ((size_t)myrow * NT64 + (J * 2 + wn)) * 3;
        p[0] = g1; p[1] = g2; p[2] = g3;
    }

    // ---- col-side (I != J): per n, top-3 of this col's 64 rows ----
    // lane-local insert3 over (m,i) [16 vals], then butterfly over quad
    // (lane bits 4,5 -> shfl_xor 16, 32). Column = j0 + wn*64 + n*16 + m_lane;
    // its 64-row range is tile index I*2 + wm.
    if (I != J) {
        #pragma unroll
        for (int n = 0; n < 4; ++n) {
            float c1 = -2.f, c2 = -2.f, c3 = -2.f;
            #pragma unroll
            for (int m = 0; m < 4; ++m)
                #pragma unroll
                for (int i = 0; i < 4; ++i) {
                    const float v  = acc[m][n][i];
                    const float u1 = fminf(c1, v);
                    c1 = fmaxf(c1, v);
                    const float u2 = fminf(c2, u1);
                    c2 = fmaxf(c2, u1);
                    c3 = fmaxf(c3, u2);
                }
            #pragma unroll
            for (int d = 16; d < 64; d <<= 1) {
                const float b1 = __shfl_xor(c1, d, 64);
                const float b2 = __shfl_xor(c2, d, 64);
                const float b3 = __shfl_xor(c3, d, 64);
                const float n2 = fmaxf(fminf(c1, b1), fmaxf(c2, b2));
                const float n3 = fmaxf(fmaxf(c3, b3),
                                       fmaxf(fminf(c1, b2), fminf(c2, b1)));
                c1 = fmaxf(c1, b1); c2 = n2; c3 = n3;
            }
            if (quad == 0) {
                const int col = j0 + wn * 64 + n * 16 + m_lane;
                float* p = M3 + ((size_t)col * NT64 + (I * 2 + wm)) * 3;
                p[0] = c1; p[1] = c2; p[2] = c3;
            }
        }
    }
}

// ---------------------------------------------------------------------------
// Kernel 3: exact top-5 per row from the 128 stored triples + per-block
// partial of the loss sum. NO single-address atomics (r4: removing the 2048
// same-address atomicAdds saved ~25-30us). Kernel 4 reduces the partials.
// ---------------------------------------------------------------------------
__global__ __launch_bounds__(256) void select_loss_kernel(const _Float16* __restrict__ xnh,
                                                          const float* __restrict__ M3,
                                                          float* __restrict__ partials) {
    const int wv = threadIdx.x >> 6, lane = threadIdx.x & 63;
    const int row = blockIdx.x * 4 + wv;
    const float* p = M3 + (size_t)row * NT64 * 3 + lane * 6;
    float a[3], b[3];
    a[0] = p[0]; a[1] = p[1]; a[2] = p[2];
    b[0] = p[3]; b[1] = p[4]; b[2] = p[5];

    float t[KNN];
    {
        float c[KNN] = { a[0], a[1], a[2], -2.f, -2.f };
        const float bb[KNN] = { b[0], b[1], b[2], -2.f, -2.f };
        merge5(c, bb);
        #pragma unroll
        for (int d = 1; d < 64; d <<= 1) {
            float o[KNN];
            #pragma unroll
            for (int k = 0; k < KNN; ++k) o[k] = __shfl_xor(c[k], d, 64);
            merge5(c, o);
        }
        #pragma unroll
        for (int k = 0; k < KNN; ++k) t[k] = c[k];
    }

    // flag tiles whose stored 3rd could hide a missed top-5 value
    const unsigned long long ba = __ballot(a[2] >= t[4]);
    const unsigned long long bb_ = __ballot(b[2] >= t[4]);
    if (ba | bb_) {
        // rebuild the pool top-5 excluding flagged tiles
        const bool fA = (ba >> lane) & 1ull, fB = (bb_ >> lane) & 1ull;
        float c[KNN] = { fA ? -2.f : a[0], fA ? -2.f : a[1], fA ? -2.f : a[2],
                         -2.f, -2.f };
        const float b5[KNN] = { fB ? -2.f : b[0], fB ? -2.f : b[1],
                                fB ? -2.f : b[2], -2.f, -2.f };
        merge5(c, b5);
        #pragma unroll
        for (int d = 1; d < 64; d <<= 1) {
            float o[KNN];
            #pragma unroll
            for (int k = 0; k < KNN; ++k) o[k] = __shfl_xor(c[k], d, 64);
            merge5(c, o);
        }
        #pragma unroll
        for (int k = 0; k < KNN; ++k) t[k] = c[k];

        // exactly recompute each flagged 64-col tile (whole wave, 1 col/lane)
        unsigned long long fl[2] = { ba, bb_ };
        #pragma unroll
        for (int h = 0; h < 2; ++h) {
            unsigned long long m = fl[h];
            while (m) {
                const int l = __ffsll((long long)m) - 1;
                m &= m - 1;
                const int jt2 = 2 * l + h;
                const int col = jt2 * 64 + lane;
                const _Float16* rp = xnh + (size_t)row * DIM;
                const _Float16* cp = xnh + (size_t)col * DIM;
                float d = 0.f;
                for (int k8 = 0; k8 < DIM / 8; ++k8) {
                    const f16x8 rv = *(const f16x8*)(rp + k8 * 8);
                    const f16x8 cv = *(const f16x8*)(cp + k8 * 8);
                    #pragma unroll
                    for (int e = 0; e < 8; ++e)
                        d += (float)rv[e] * (float)cv[e];
                }
                if (col == row) d = -2.f;
                float c2[KNN] = { d, -2.f, -2.f, -2.f, -2.f };
                #pragma unroll
                for (int dd = 1; dd < 64; dd <<= 1) {
                    float o[KNN];
                    #pragma unroll
                    for (int k = 0; k < KNN; ++k) o[k] = __shfl_xor(c2[k], dd, 64);
                    merge5(c2, o);
                }
                merge5(t, c2);
            }
        }
    }

    // loss term: unit vectors -> dist_k = sqrt(2 - 2*dot_k)
    float s = 0.f;
    #pragma unroll
    for (int k = 0; k < KNN; ++k) s += sqrtf(fmaxf(2.f - 2.f * t[k], 0.f));
    const float val = logf(s * (1.f / KNN) + EPSV);

    __shared__ float red[4];
    if (lane == 0) red[wv] = val;
    __syncthreads();
    if (threadIdx.x == 0)
        partials[blockIdx.x] = red[0] + red[1] + red[2] + red[3];
}

// ---------------------------------------------------------------------------
// Kernel 4: reduce the 2048 per-block partials -> loss. One block.
// ---------------------------------------------------------------------------
__global__ __launch_bounds__(256) void reduce_kernel(const float* __restrict__ partials,
                                                     float* __restrict__ out) {
    const int tid = threadIdx.x, lane = tid & 63, wv = tid >> 6;
    float s = 0.f;
    #pragma unroll
    for (int q = 0; q < NSEL / 256; ++q) s += partials[tid + q * 256];
    #pragma unroll
    for (int off = 1; off < 64; off <<= 1) s += __shfl_xor(s, off, 64);
    __shared__ float red[4];
    if (lane == 0) red[wv] = s;
    __syncthreads();
    if (tid == 0)
        *out = -(red[0] + red[1] + red[2] + red[3]) / (float)NROWS;
}

// ---------------------------------------------------------------------------
extern "C" void kernel_launch(void* const* d_in, const int* in_sizes, int n_in,
                              void* d_out, int out_size, void* d_ws, size_t ws_size,
                              hipStream_t stream) {
    const float* x = (const float*)d_in[0];
    float* out = (float*)d_out;
    char* ws = (char*)d_ws;

    _Float16* xnh = (_Float16*)ws;                                     // 8 MB
    float* M3 = (float*)(ws + (size_t)NROWS * DIM * sizeof(_Float16)); // 12.6 MB
    float* partials = M3 + (size_t)NROWS * NT64 * 3;                   // 8 KB

    norm_kernel<<<NROWS / 4, 256, 0, stream>>>(x, xnh);
    dots_top3_kernel<<<NWORK, 256, 0, stream>>>(xnh, M3);
    select_loss_kernel<<<NSEL, 256, 0, stream>>>(xnh, M3, partials);
    reduce_kernel<<<1, 256, 0, stream>>>(partials, out);
}

// Round 7
// 158.868 us; speedup vs baseline: 1.5127x; 1.5127x over previous
//
#include <hip/hip_runtime.h>
#include <math.h>

// Problem constants (x: [8192, 512] fp32, K=5, eps=1e-8, scalar fp32 loss)
#define NROWS 8192
#define DIM   512
#define KNN   5
#define EPSV  1e-8f

// GEMM tiling: 128x128 block tile, BK=32, 4 waves (2x2), each wave 4x4 of
// 16x16x32 MFMA. Round-7: counted-vmcnt double-buffer (T3-min + T4).
//  - r1 failure mode understood: __syncthreads = vmcnt(0) drain per iter, so
//    its "prefetch" never stayed in flight. Here raw s_barrier + inline-asm
//    s_waitcnt vmcnt(4): the 4 loads for tile ks+1 remain outstanding across
//    the barrier while tile ks computes. Only the last iter drains to 0.
//  - r6 failure mode recorded: direct-from-global fragments destroy
//    coalescing (16 lines/instr vs 1) -> keep global_load_lds staging.
#define BM 128
#define BN 128
#define BK 32
#define NT (NROWS / BM)        // 64 tile indices per dimension
#define NT64 (NROWS / 64)      // 128 64-col tiles per row
#define NKS (DIM / BK)         // 16 K-steps
#define NWORK 2080             // 64*65/2 upper-triangular work blocks (= 8*260)
#define NSEL (NROWS / 4)       // select blocks (4 waves, 1 row/wave) = 2048

typedef __attribute__((ext_vector_type(8))) _Float16 f16x8;
typedef __attribute__((ext_vector_type(4))) float    f32x4;

// async global->LDS, 16B per lane (LDS dest must be wave-uniform base + lane*16)
__device__ __forceinline__ void gload16(const _Float16* g, _Float16* l) {
    __builtin_amdgcn_global_load_lds(
        (const __attribute__((address_space(1))) void*)g,
        (__attribute__((address_space(3))) void*)l, 16, 0, 0);
}

__device__ __forceinline__ void cmpswap(float& a, float& b) {
    const float hi = fmaxf(a, b), lo = fminf(a, b);
    a = hi; b = lo;
}

// merge two sorted-descending 5-lists -> top-5 (into a).
__device__ __forceinline__ void merge5(float a[KNN], const float b[KNN]) {
    const float c0 = fmaxf(a[0], b[0]);
    const float c1 = fmaxf(fmaxf(a[1], b[1]), fminf(a[0], b[0]));
    const float c2 = fmaxf(fmaxf(a[2], b[2]),
                           fmaxf(fminf(a[0], b[1]), fminf(a[1], b[0])));
    const float c3 = fmaxf(fmaxf(a[3], b[3]),
                           fmaxf(fminf(a[0], b[2]),
                                 fmaxf(fminf(a[1], b[1]), fminf(a[2], b[0]))));
    const float c4 = fmaxf(fmaxf(a[4], b[4]),
                           fmaxf(fmaxf(fminf(a[0], b[3]), fminf(a[1], b[2])),
                                 fmaxf(fminf(a[2], b[1]), fminf(a[3], b[0]))));
    a[0] = c0; a[1] = c1; a[2] = c2; a[3] = c3; a[4] = c4;
}

// ---------------------------------------------------------------------------
// Kernel 1: row-normalize x (fp32) -> xn (f16). One WAVE per row, 16B stores.
// ---------------------------------------------------------------------------
__global__ __launch_bounds__(256) void norm_kernel(const float* __restrict__ x,
                                                   _Float16* __restrict__ xnh) {
    const int wv = threadIdx.x >> 6, lane = threadIdx.x & 63;
    const int row = blockIdx.x * 4 + wv;
    const float4* xr = (const float4*)(x + (size_t)row * DIM) + lane * 2;
    const float4 a = xr[0];
    const float4 b = xr[1];
    float s = a.x * a.x + a.y * a.y + a.z * a.z + a.w * a.w
            + b.x * b.x + b.y * b.y + b.z * b.z + b.w * b.w;
    #pragma unroll
    for (int off = 1; off < 64; off <<= 1) s += __shfl_xor(s, off, 64);
    const float inv = 1.0f / sqrtf(s);
    const f16x8 h = { (_Float16)(a.x * inv), (_Float16)(a.y * inv),
                      (_Float16)(a.z * inv), (_Float16)(a.w * inv),
                      (_Float16)(b.x * inv), (_Float16)(b.y * inv),
                      (_Float16)(b.z * inv), (_Float16)(b.w * inv) };
    *(f16x8*)(xnh + (size_t)row * DIM + lane * 8) = h;
}

// ---------------------------------------------------------------------------
// Kernel 2: TRIANGULAR Gram-tile GEMM + per-(row, 64-col-tile) top-3.
// Round-7 sync structure (NEW TEMPLATE — ordering ledger):
//   writer->reader : each wave issues exactly 4 gload_lds per tile;
//                    "s_waitcnt vmcnt(4); s_barrier" (single asm, "memory")
//                    => all waves' tile-ks loads landed before any ds_read.
//   reader->rewrite: trailing "s_barrier" before the buffer is re-staged
//                    two iterations later.
//   vmcnt counting : FIFO per m135; uniform 4 VMEM ops/wave/iter; only the
//                    epilogue iteration drains vmcnt(0).
// Everything else is the verified r4 kernel: coalesced global_load_lds
// (r6: direct loads are request-bound, 2x slower), XOR chunk swizzle
// (r1: conflicts 4.26M->0), XCD super-tile map (r2: FETCH 33->23MB).
// ---------------------------------------------------------------------------
__global__ __launch_bounds__(256) void dots_top3_kernel(const _Float16* __restrict__ xnh,
                                                        float* __restrict__ M3) {
    // ---- work-index decode: launch b -> XCD-contiguous work item w -> (I,J)
    // XCD x = b&7 gets slots w in [x*260, (x+1)*260); work enumerated over
    // super-tiles (SI,SJ>=SI) of 8x8 tiles; diag super-tiles hold the 36
    // upper-tri pairs, off-diag hold all 64. Totals: 8*36 + 28*64 = 2080.
    int I, J;
    {
        int rem = (int)(blockIdx.x & 7) * (NWORK / 8) + (int)(blockIdx.x >> 3);
        int found = 0;
        for (int SI = 0; SI < 8 && !found; ++SI) {
            for (int SJ = SI; SJ < 8 && !found; ++SJ) {
                const int sz = (SI == SJ) ? 36 : 64;
                if (rem < sz) {
                    if (SI == SJ) {
                        int i = 0, r2 = rem;
                        while (r2 >= 8 - i) { r2 -= 8 - i; ++i; }
                        I = SI * 8 + i;
                        J = SJ * 8 + i + r2;
                    } else {
                        I = SI * 8 + (rem >> 3);
                        J = SJ * 8 + (rem & 7);
                    }
                    found = 1;
                } else {
                    rem -= sz;
                }
            }
        }
    }

    __shared__ __align__(16) _Float16 As[2][BM * BK];   // 2 x 8 KB
    __shared__ __align__(16) _Float16 Bs[2][BN * BK];   // 2 x 8 KB

    const int tid    = threadIdx.x;
    const int lane   = tid & 63;
    const int wv     = tid >> 6;
    const int wm     = wv >> 1;          // wave row half (0..1)
    const int wn     = wv & 1;           // wave col half (0..1)
    const int m_lane = lane & 15;        // MFMA: m (A) / n (B) / col (C)
    const int quad   = lane >> 4;        // MFMA: k-chunk (A,B) / row-group (C)

    const int i0 = I * BM;
    const int j0 = J * BN;

    // lane (quad, m_lane) owns row rowlocal (its (m,i) = (m_lane>>2, m_lane&3))
    const int rowlocal = (m_lane >> 2) * 16 + quad * 4 + (m_lane & 3);
    const int myrow    = i0 + wm * 64 + rowlocal;

    // fragment-read chunk swizzle: (row>>1)&3 == (m_lane>>1)&3 for every m, wm
    const int rchunk = (quad ^ ((m_lane >> 1) & 3)) * 8;

    // staging addresses (pre-swizzled global source; LDS written linearly).
    // LDS slot s (row r = s>>2, chunk kk = s&3) receives global chunk
    // kk ^ ((r>>1)&3); involution, matched by rchunk on the read side.
    const int s0 = tid, s1 = tid + 256;
    const int r0g = s0 >> 2, r1g = s1 >> 2;
    const int kg0 = (s0 & 3) ^ ((s0 >> 3) & 3);
    const int kg1 = (s1 & 3) ^ ((s1 >> 3) & 3);
    const _Float16* gA0 = xnh + (size_t)(i0 + r0g) * DIM + kg0 * 8;
    const _Float16* gA1 = xnh + (size_t)(i0 + r1g) * DIM + kg1 * 8;
    const _Float16* gB0 = xnh + (size_t)(j0 + r0g) * DIM + kg0 * 8;
    const _Float16* gB1 = xnh + (size_t)(j0 + r1g) * DIM + kg1 * 8;

    f32x4 acc[4][4];
    #pragma unroll
    for (int m = 0; m < 4; ++m)
        #pragma unroll
        for (int n = 0; n < 4; ++n)
            acc[m][n] = (f32x4){0.f, 0.f, 0.f, 0.f};

    _Float16* a_cur = As[0]; _Float16* b_cur = Bs[0];
    _Float16* a_nxt = As[1]; _Float16* b_nxt = Bs[1];

    // prologue: stage tile 0 (4 VMEM ops/thread)
    gload16(gA0, a_cur + s0 * 8);
    gload16(gA1, a_cur + s1 * 8);
    gload16(gB0, b_cur + s0 * 8);
    gload16(gB1, b_cur + s1 * 8);

    for (int ks = 0; ks < NKS; ++ks) {
        if (ks + 1 < NKS) {
            const int k0 = (ks + 1) * BK;
            gload16(gA0 + k0, a_nxt + s0 * 8);
            gload16(gA1 + k0, a_nxt + s1 * 8);
            gload16(gB0 + k0, b_nxt + s0 * 8);
            gload16(gB1 + k0, b_nxt + s1 * 8);
            // wait ONLY the 4 oldest (tile ks); the 4 just issued stay in
            // flight across the barrier. Single asm: nothing reorders between
            // the wait and the barrier.
            asm volatile("s_waitcnt vmcnt(4)\n\ts_barrier" ::: "memory");
        } else {
            asm volatile("s_waitcnt vmcnt(0)\n\ts_barrier" ::: "memory");
        }

        f16x8 af[4], bf[4];
        #pragma unroll
        for (int m = 0; m < 4; ++m)
            af[m] = *(const f16x8*)(a_cur + (wm * 64 + m * 16 + m_lane) * BK + rchunk);
        #pragma unroll
        for (int n = 0; n < 4; ++n)
            bf[n] = *(const f16x8*)(b_cur + (wn * 64 + n * 16 + m_lane) * BK + rchunk);
        #pragma unroll
        for (int m = 0; m < 4; ++m)
            #pragma unroll
            for (int n = 0; n < 4; ++n)
                acc[m][n] = __builtin_amdgcn_mfma_f32_16x16x32_f16(af[m], bf[n], acc[m][n], 0, 0, 0);

        // readers done with buf[cur] before iter ks+1 re-stages it.
        asm volatile("s_barrier" ::: "memory");

        _Float16* t;
        t = a_cur; a_cur = a_nxt; a_nxt = t;
        t = b_cur; b_cur = b_nxt; b_nxt = t;
    }

    // diagonal mask: self-dot only when I==J && wm==wn && m==n.
    const bool diag = (I == J) && (wm == wn);
    #pragma unroll
    for (int m = 0; m < 4; ++m)
        #pragma unroll
        for (int i = 0; i < 4; ++i)
            acc[m][m][i] = (diag && (quad * 4 + i) == m_lane) ? -2.f : acc[m][m][i];

    // ---- row-side: per (m,i), top-3 of this row's 64 cols (butterfly) ----
    float g1 = -2.f, g2 = -2.f, g3 = -2.f;
    #pragma unroll
    for (int m = 0; m < 4; ++m) {
        #pragma unroll
        for (int i = 0; i < 4; ++i) {
            float v0 = acc[m][0][i], v1 = acc[m][1][i];
            float v2 = acc[m][2][i], v3 = acc[m][3][i];
            cmpswap(v0, v1); cmpswap(v2, v3);
            cmpswap(v0, v2); cmpswap(v1, v3);
            cmpswap(v1, v2);                     // v0>=v1>=v2 (>=v3, dropped)
            float a1 = v0, a2 = v1, a3 = v2;
            #pragma unroll
            for (int d = 1; d < 16; d <<= 1) {
                const float b1 = __shfl_xor(a1, d, 64);
                const float b2 = __shfl_xor(a2, d, 64);
                const float b3 = __shfl_xor(a3, d, 64);
                const float n1 = fmaxf(a1, b1);
                const float n2 = fmaxf(fminf(a1, b1), fmaxf(a2, b2));
                const float n3 = fmaxf(fmaxf(a3, b3),
                                       fmaxf(fminf(a1, b2), fminf(a2, b1)));
                a1 = n1; a2 = n2; a3 = n3;
            }
            const bool own = (m_lane == m * 4 + i);
            g1 = own ? a1 : g1; g2 = own ? a2 : g2; g3 = own ? a3 : g3;
        }
    }
    {
        float* p = M3 + ((size_t)myrow * NT64 + (J * 2 + wn)) * 3;
        p[0] = g1; p[1] = g2; p[2] = g3;
    }

    // ---- col-side (I != J): per n, top-3 of this col's 64 rows ----
    // lane-local insert3 over (m,i) [16 vals], then butterfly over quad
    // (lane bits 4,5 -> shfl_xor 16, 32). Column = j0 + wn*64 + n*16 + m_lane;
    // its 64-row range is tile index I*2 + wm.
    if (I != J) {
        #pragma unroll
        for (int n = 0; n < 4; ++n) {
            float c1 = -2.f, c2 = -2.f, c3 = -2.f;
            #pragma unroll
            for (int m = 0; m < 4; ++m)
                #pragma unroll
                for (int i = 0; i < 4; ++i) {
                    const float v  = acc[m][n][i];
                    const float u1 = fminf(c1, v);
                    c1 = fmaxf(c1, v);
                    const float u2 = fminf(c2, u1);
                    c2 = fmaxf(c2, u1);
                    c3 = fmaxf(c3, u2);
                }
            #pragma unroll
            for (int d = 16; d < 64; d <<= 1) {
                const float b1 = __shfl_xor(c1, d, 64);
                const float b2 = __shfl_xor(c2, d, 64);
                const float b3 = __shfl_xor(c3, d, 64);
                const float n2 = fmaxf(fminf(c1, b1), fmaxf(c2, b2));
                const float n3 = fmaxf(fmaxf(c3, b3),
                                       fmaxf(fminf(c1, b2), fminf(c2, b1)));
                c1 = fmaxf(c1, b1); c2 = n2; c3 = n3;
            }
            if (quad == 0) {
                const int col = j0 + wn * 64 + n * 16 + m_lane;
                float* p = M3 + ((size_t)col * NT64 + (I * 2 + wm)) * 3;
                p[0] = c1; p[1] = c2; p[2] = c3;
            }
        }
    }
}

// ---------------------------------------------------------------------------
// Kernel 3: exact top-5 per row from the 128 stored triples + per-block
// partial of the loss sum. NO single-address atomics (r4: removing the 2048
// same-address atomicAdds saved ~25-30us). Kernel 4 reduces the partials.
// ---------------------------------------------------------------------------
__global__ __launch_bounds__(256) void select_loss_kernel(const _Float16* __restrict__ xnh,
                                                          const float* __restrict__ M3,
                                                          float* __restrict__ partials) {
    const int wv = threadIdx.x >> 6, lane = threadIdx.x & 63;
    const int row = blockIdx.x * 4 + wv;
    const float* p = M3 + (size_t)row * NT64 * 3 + lane * 6;
    float a[3], b[3];
    a[0] = p[0]; a[1] = p[1]; a[2] = p[2];
    b[0] = p[3]; b[1] = p[4]; b[2] = p[5];

    float t[KNN];
    {
        float c[KNN] = { a[0], a[1], a[2], -2.f, -2.f };
        const float bb[KNN] = { b[0], b[1], b[2], -2.f, -2.f };
        merge5(c, bb);
        #pragma unroll
        for (int d = 1; d < 64; d <<= 1) {
            float o[KNN];
            #pragma unroll
            for (int k = 0; k < KNN; ++k) o[k] = __shfl_xor(c[k], d, 64);
            merge5(c, o);
        }
        #pragma unroll
        for (int k = 0; k < KNN; ++k) t[k] = c[k];
    }

    // flag tiles whose stored 3rd could hide a missed top-5 value
    const unsigned long long ba = __ballot(a[2] >= t[4]);
    const unsigned long long bb_ = __ballot(b[2] >= t[4]);
    if (ba | bb_) {
        // rebuild the pool top-5 excluding flagged tiles
        const bool fA = (ba >> lane) & 1ull, fB = (bb_ >> lane) & 1ull;
        float c[KNN] = { fA ? -2.f : a[0], fA ? -2.f : a[1], fA ? -2.f : a[2],
                         -2.f, -2.f };
        const float b5[KNN] = { fB ? -2.f : b[0], fB ? -2.f : b[1],
                                fB ? -2.f : b[2], -2.f, -2.f };
        merge5(c, b5);
        #pragma unroll
        for (int d = 1; d < 64; d <<= 1) {
            float o[KNN];
            #pragma unroll
            for (int k = 0; k < KNN; ++k) o[k] = __shfl_xor(c[k], d, 64);
            merge5(c, o);
        }
        #pragma unroll
        for (int k = 0; k < KNN; ++k) t[k] = c[k];

        // exactly recompute each flagged 64-col tile (whole wave, 1 col/lane)
        unsigned long long fl[2] = { ba, bb_ };
        #pragma unroll
        for (int h = 0; h < 2; ++h) {
            unsigned long long m = fl[h];
            while (m) {
                const int l = __ffsll((long long)m) - 1;
                m &= m - 1;
                const int jt2 = 2 * l + h;
                const int col = jt2 * 64 + lane;
                const _Float16* rp = xnh + (size_t)row * DIM;
                const _Float16* cp = xnh + (size_t)col * DIM;
                float d = 0.f;
                for (int k8 = 0; k8 < DIM / 8; ++k8) {
                    const f16x8 rv = *(const f16x8*)(rp + k8 * 8);
                    const f16x8 cv = *(const f16x8*)(cp + k8 * 8);
                    #pragma unroll
                    for (int e = 0; e < 8; ++e)
                        d += (float)rv[e] * (float)cv[e];
                }
                if (col == row) d = -2.f;
                float c2[KNN] = { d, -2.f, -2.f, -2.f, -2.f };
                #pragma unroll
                for (int dd = 1; dd < 64; dd <<= 1) {
                    float o[KNN];
                    #pragma unroll
                    for (int k = 0; k < KNN; ++k) o[k] = __shfl_xor(c2[k], dd, 64);
                    merge5(c2, o);
                }
                merge5(t, c2);
            }
        }
    }

    // loss term: unit vectors -> dist_k = sqrt(2 - 2*dot_k)
    float s = 0.f;
    #pragma unroll
    for (int k = 0; k < KNN; ++k) s += sqrtf(fmaxf(2.f - 2.f * t[k], 0.f));
    const float val = logf(s * (1.f / KNN) + EPSV);

    __shared__ float red[4];
    if (lane == 0) red[wv] = val;
    __syncthreads();
    if (threadIdx.x == 0)
        partials[blockIdx.x] = red[0] + red[1] + red[2] + red[3];
}

// ---------------------------------------------------------------------------
// Kernel 4: reduce the 2048 per-block partials -> loss. One block.
// ---------------------------------------------------------------------------
__global__ __launch_bounds__(256) void reduce_kernel(const float* __restrict__ partials,
                                                     float* __restrict__ out) {
    const int tid = threadIdx.x, lane = tid & 63, wv = tid >> 6;
    float s = 0.f;
    #pragma unroll
    for (int q = 0; q < NSEL / 256; ++q) s += partials[tid + q * 256];
    #pragma unroll
    for (int off = 1; off < 64; off <<= 1) s += __shfl_xor(s, off, 64);
    __shared__ float red[4];
    if (lane == 0) red[wv] = s;
    __syncthreads();
    if (tid == 0)
        *out = -(red[0] + red[1] + red[2] + red[3]) / (float)NROWS;
}

// ---------------------------------------------------------------------------
extern "C" void kernel_launch(void* const* d_in, const int* in_sizes, int n_in,
                              void* d_out, int out_size, void* d_ws, size_t ws_size,
                              hipStream_t stream) {
    const float* x = (const float*)d_in[0];
    float* out = (float*)d_out;
    char* ws = (char*)d_ws;

    _Float16* xnh = (_Float16*)ws;                                     // 8 MB
    float* M3 = (float*)(ws + (size_t)NROWS * DIM * sizeof(_Float16)); // 12.6 MB
    float* partials = M3 + (size_t)NROWS * NT64 * 3;                   // 8 KB

    norm_kernel<<<NROWS / 4, 256, 0, stream>>>(x, xnh);
    dots_top3_kernel<<<NWORK, 256, 0, stream>>>(xnh, M3);
    select_loss_kernel<<<NSEL, 256, 0, stream>>>(xnh, M3, partials);
    reduce_kernel<<<1, 256, 0, stream>>>(partials, out);
}

// Round 8
// 149.136 us; speedup vs baseline: 1.6114x; 1.0653x over previous
//
#include <hip/hip_runtime.h>
#include <math.h>

// Problem constants (x: [8192, 512] fp32, K=5, eps=1e-8, scalar fp32 loss)
#define NROWS 8192
#define DIM   512
#define KNN   5
#define EPSV  1e-8f

// GEMM tiling: 128x128 block tile, BK=32, 4 waves (2x2), each wave 4x4 of
// 16x16x32 MFMA. Round-8: DEPTH-2 prefetch, 3 LDS buffers, ONE barrier per
// K-step (r7 was depth-1, 2 barriers: its prefetch cover ~= one compute
// phase ~= L2 latency -> zero slack -> null). Here a tile's loads issue two
// full compute phases (~600+ cyc) before their vmcnt wait.
#define BM 128
#define BN 128
#define BK 32
#define NT (NROWS / BM)        // 64 tile indices per dimension
#define NT64 (NROWS / 64)      // 128 64-col tiles per row
#define NKS (DIM / BK)         // 16 K-steps
#define NWORK 2080             // 64*65/2 upper-triangular work blocks (= 8*260)
#define NSEL (NROWS / 4)       // select blocks (4 waves, 1 row/wave) = 2048

typedef __attribute__((ext_vector_type(8))) _Float16 f16x8;
typedef __attribute__((ext_vector_type(4))) float    f32x4;

// async global->LDS, 16B per lane (LDS dest must be wave-uniform base + lane*16)
__device__ __forceinline__ void gload16(const _Float16* g, _Float16* l) {
    __builtin_amdgcn_global_load_lds(
        (const __attribute__((address_space(1))) void*)g,
        (__attribute__((address_space(3))) void*)l, 16, 0, 0);
}

__device__ __forceinline__ void cmpswap(float& a, float& b) {
    const float hi = fmaxf(a, b), lo = fminf(a, b);
    a = hi; b = lo;
}

// merge two sorted-descending 5-lists -> top-5 (into a).
__device__ __forceinline__ void merge5(float a[KNN], const float b[KNN]) {
    const float c0 = fmaxf(a[0], b[0]);
    const float c1 = fmaxf(fmaxf(a[1], b[1]), fminf(a[0], b[0]));
    const float c2 = fmaxf(fmaxf(a[2], b[2]),
                           fmaxf(fminf(a[0], b[1]), fminf(a[1], b[0])));
    const float c3 = fmaxf(fmaxf(a[3], b[3]),
                           fmaxf(fminf(a[0], b[2]),
                                 fmaxf(fminf(a[1], b[1]), fminf(a[2], b[0]))));
    const float c4 = fmaxf(fmaxf(a[4], b[4]),
                           fmaxf(fmaxf(fminf(a[0], b[3]), fminf(a[1], b[2])),
                                 fmaxf(fminf(a[2], b[1]), fminf(a[3], b[0]))));
    a[0] = c0; a[1] = c1; a[2] = c2; a[3] = c3; a[4] = c4;
}

// ---------------------------------------------------------------------------
// Kernel 1: row-normalize x (fp32) -> xn (f16). One WAVE per row, 16B stores.
// ---------------------------------------------------------------------------
__global__ __launch_bounds__(256) void norm_kernel(const float* __restrict__ x,
                                                   _Float16* __restrict__ xnh) {
    const int wv = threadIdx.x >> 6, lane = threadIdx.x & 63;
    const int row = blockIdx.x * 4 + wv;
    const float4* xr = (const float4*)(x + (size_t)row * DIM) + lane * 2;
    const float4 a = xr[0];
    const float4 b = xr[1];
    float s = a.x * a.x + a.y * a.y + a.z * a.z + a.w * a.w
            + b.x * b.x + b.y * b.y + b.z * b.z + b.w * b.w;
    #pragma unroll
    for (int off = 1; off < 64; off <<= 1) s += __shfl_xor(s, off, 64);
    const float inv = 1.0f / sqrtf(s);
    const f16x8 h = { (_Float16)(a.x * inv), (_Float16)(a.y * inv),
                      (_Float16)(a.z * inv), (_Float16)(a.w * inv),
                      (_Float16)(b.x * inv), (_Float16)(b.y * inv),
                      (_Float16)(b.z * inv), (_Float16)(b.w * inv) };
    *(f16x8*)(xnh + (size_t)row * DIM + lane * 8) = h;
}

// ---------------------------------------------------------------------------
// Kernel 2: TRIANGULAR Gram-tile GEMM + per-(row, 64-col-tile) top-3.
// Round-8 sync structure (NEW TEMPLATE — ordering ledger):
//   per iter ks: "s_waitcnt vmcnt(4); s_barrier" -> stage tile ks+2 into
//   buf[(ks+2)%3] -> ds_read buf[ks%3] -> 16 MFMA.  (full unroll: buffer
//   indices fold to constants; NO second barrier.)
//   writer->reader : wave has tiles {ks, ks+1} outstanding (8 VMEM) at the
//     wait; vmcnt(4) = tile-ks landed, for ALL waves after the barrier.
//   reader->rewrite: between barriers the block writes (ks+2)%3 and reads
//     ks%3 (disjoint mod 3); buf[(ks+2)%3] was last read at iter ks-1,
//     sealed by this iter's barrier.
//   counting: uniform 4 VMEM/wave/iter (FIFO, m135); only ks=15 drains 0.
//   Epilogue uses no LDS -> no trailing barrier.
// Kept: coalesced global_load_lds (r6: direct loads request-bound, 2x slow),
// XOR chunk swizzle (r1: conflicts 4.26M->0), XCD super-tile map (r2).
// ---------------------------------------------------------------------------
__global__ __launch_bounds__(256) void dots_top3_kernel(const _Float16* __restrict__ xnh,
                                                        float* __restrict__ M3) {
    // ---- work-index decode: launch b -> XCD-contiguous work item w -> (I,J)
    // XCD x = b&7 gets slots w in [x*260, (x+1)*260); work enumerated over
    // super-tiles (SI,SJ>=SI) of 8x8 tiles; diag super-tiles hold the 36
    // upper-tri pairs, off-diag hold all 64. Totals: 8*36 + 28*64 = 2080.
    int I, J;
    {
        int rem = (int)(blockIdx.x & 7) * (NWORK / 8) + (int)(blockIdx.x >> 3);
        int found = 0;
        for (int SI = 0; SI < 8 && !found; ++SI) {
            for (int SJ = SI; SJ < 8 && !found; ++SJ) {
                const int sz = (SI == SJ) ? 36 : 64;
                if (rem < sz) {
                    if (SI == SJ) {
                        int i = 0, r2 = rem;
                        while (r2 >= 8 - i) { r2 -= 8 - i; ++i; }
                        I = SI * 8 + i;
                        J = SJ * 8 + i + r2;
                    } else {
                        I = SI * 8 + (rem >> 3);
                        J = SJ * 8 + (rem & 7);
                    }
                    found = 1;
                } else {
                    rem -= sz;
                }
            }
        }
    }

    __shared__ __align__(16) _Float16 As[3][BM * BK];   // 3 x 8 KB
    __shared__ __align__(16) _Float16 Bs[3][BN * BK];   // 3 x 8 KB

    const int tid    = threadIdx.x;
    const int lane   = tid & 63;
    const int wv     = tid >> 6;
    const int wm     = wv >> 1;          // wave row half (0..1)
    const int wn     = wv & 1;           // wave col half (0..1)
    const int m_lane = lane & 15;        // MFMA: m (A) / n (B) / col (C)
    const int quad   = lane >> 4;        // MFMA: k-chunk (A,B) / row-group (C)

    const int i0 = I * BM;
    const int j0 = J * BN;

    // lane (quad, m_lane) owns row rowlocal (its (m,i) = (m_lane>>2, m_lane&3))
    const int rowlocal = (m_lane >> 2) * 16 + quad * 4 + (m_lane & 3);
    const int myrow    = i0 + wm * 64 + rowlocal;

    // fragment-read chunk swizzle: (row>>1)&3 == (m_lane>>1)&3 for every m, wm
    const int rchunk = (quad ^ ((m_lane >> 1) & 3)) * 8;

    // staging addresses (pre-swizzled global source; LDS written linearly).
    // LDS slot s (row r = s>>2, chunk kk = s&3) receives global chunk
    // kk ^ ((r>>1)&3); involution, matched by rchunk on the read side.
    const int s0 = tid, s1 = tid + 256;
    const int r0g = s0 >> 2, r1g = s1 >> 2;
    const int kg0 = (s0 & 3) ^ ((s0 >> 3) & 3);
    const int kg1 = (s1 & 3) ^ ((s1 >> 3) & 3);
    const _Float16* gA0 = xnh + (size_t)(i0 + r0g) * DIM + kg0 * 8;
    const _Float16* gA1 = xnh + (size_t)(i0 + r1g) * DIM + kg1 * 8;
    const _Float16* gB0 = xnh + (size_t)(j0 + r0g) * DIM + kg0 * 8;
    const _Float16* gB1 = xnh + (size_t)(j0 + r1g) * DIM + kg1 * 8;

    #define STAGE(kt_, abuf_, bbuf_)                       \
        do {                                               \
            const int k0_ = (kt_) * BK;                    \
            gload16(gA0 + k0_, (abuf_) + s0 * 8);          \
            gload16(gA1 + k0_, (abuf_) + s1 * 8);          \
            gload16(gB0 + k0_, (bbuf_) + s0 * 8);          \
            gload16(gB1 + k0_, (bbuf_) + s1 * 8);          \
        } while (0)

    f32x4 acc[4][4];
    #pragma unroll
    for (int m = 0; m < 4; ++m)
        #pragma unroll
        for (int n = 0; n < 4; ++n)
            acc[m][n] = (f32x4){0.f, 0.f, 0.f, 0.f};

    // prologue: two tiles in flight (8 VMEM ops/thread)
    STAGE(0, As[0], Bs[0]);
    STAGE(1, As[1], Bs[1]);

    #pragma unroll
    for (int ks = 0; ks < NKS; ++ks) {
        if (ks < NKS - 1)
            asm volatile("s_waitcnt vmcnt(4)\n\ts_barrier" ::: "memory");
        else
            asm volatile("s_waitcnt vmcnt(0)\n\ts_barrier" ::: "memory");

        if (ks + 2 < NKS) STAGE(ks + 2, As[(ks + 2) % 3], Bs[(ks + 2) % 3]);

        const _Float16* a_cur = As[ks % 3];
        const _Float16* b_cur = Bs[ks % 3];
        f16x8 af[4], bf[4];
        #pragma unroll
        for (int m = 0; m < 4; ++m)
            af[m] = *(const f16x8*)(a_cur + (wm * 64 + m * 16 + m_lane) * BK + rchunk);
        #pragma unroll
        for (int n = 0; n < 4; ++n)
            bf[n] = *(const f16x8*)(b_cur + (wn * 64 + n * 16 + m_lane) * BK + rchunk);
        #pragma unroll
        for (int m = 0; m < 4; ++m)
            #pragma unroll
            for (int n = 0; n < 4; ++n)
                acc[m][n] = __builtin_amdgcn_mfma_f32_16x16x32_f16(af[m], bf[n], acc[m][n], 0, 0, 0);
    }
    #undef STAGE

    // diagonal mask: self-dot only when I==J && wm==wn && m==n.
    const bool diag = (I == J) && (wm == wn);
    #pragma unroll
    for (int m = 0; m < 4; ++m)
        #pragma unroll
        for (int i = 0; i < 4; ++i)
            acc[m][m][i] = (diag && (quad * 4 + i) == m_lane) ? -2.f : acc[m][m][i];

    // ---- row-side: per (m,i), top-3 of this row's 64 cols (butterfly) ----
    float g1 = -2.f, g2 = -2.f, g3 = -2.f;
    #pragma unroll
    for (int m = 0; m < 4; ++m) {
        #pragma unroll
        for (int i = 0; i < 4; ++i) {
            float v0 = acc[m][0][i], v1 = acc[m][1][i];
            float v2 = acc[m][2][i], v3 = acc[m][3][i];
            cmpswap(v0, v1); cmpswap(v2, v3);
            cmpswap(v0, v2); cmpswap(v1, v3);
            cmpswap(v1, v2);                     // v0>=v1>=v2 (>=v3, dropped)
            float a1 = v0, a2 = v1, a3 = v2;
            #pragma unroll
            for (int d = 1; d < 16; d <<= 1) {
                const float b1 = __shfl_xor(a1, d, 64);
                const float b2 = __shfl_xor(a2, d, 64);
                const float b3 = __shfl_xor(a3, d, 64);
                const float n1 = fmaxf(a1, b1);
                const float n2 = fmaxf(fminf(a1, b1), fmaxf(a2, b2));
                const float n3 = fmaxf(fmaxf(a3, b3),
                                       fmaxf(fminf(a1, b2), fminf(a2, b1)));
                a1 = n1; a2 = n2; a3 = n3;
            }
            const bool own = (m_lane == m * 4 + i);
            g1 = own ? a1 : g1; g2 = own ? a2 : g2; g3 = own ? a3 : g3;
        }
    }
    {
        float* p = M3 + ((size_t)myrow * NT64 + (J * 2 + wn)) * 3;
        p[0] = g1; p[1] = g2; p[2] = g3;
    }

    // ---- col-side (I != J): per n, top-3 of this col's 64 rows ----
    // lane-local insert3 over (m,i) [16 vals], then butterfly over quad
    // (lane bits 4,5 -> shfl_xor 16, 32). Column = j0 + wn*64 + n*16 + m_lane;
    // its 64-row range is tile index I*2 + wm.
    if (I != J) {
        #pragma unroll
        for (int n = 0; n < 4; ++n) {
            float c1 = -2.f, c2 = -2.f, c3 = -2.f;
            #pragma unroll
            for (int m = 0; m < 4; ++m)
                #pragma unroll
                for (int i = 0; i < 4; ++i) {
                    const float v  = acc[m][n][i];
                    const float u1 = fminf(c1, v);
                    c1 = fmaxf(c1, v);
                    const float u2 = fminf(c2, u1);
                    c2 = fmaxf(c2, u1);
                    c3 = fmaxf(c3, u2);
                }
            #pragma unroll
            for (int d = 16; d < 64; d <<= 1) {
                const float b1 = __shfl_xor(c1, d, 64);
                const float b2 = __shfl_xor(c2, d, 64);
                const float b3 = __shfl_xor(c3, d, 64);
                const float n2 = fmaxf(fminf(c1, b1), fmaxf(c2, b2));
                const float n3 = fmaxf(fmaxf(c3, b3),
                                       fmaxf(fminf(c1, b2), fminf(c2, b1)));
                c1 = fmaxf(c1, b1); c2 = n2; c3 = n3;
            }
            if (quad == 0) {
                const int col = j0 + wn * 64 + n * 16 + m_lane;
                float* p = M3 + ((size_t)col * NT64 + (I * 2 + wm)) * 3;
                p[0] = c1; p[1] = c2; p[2] = c3;
            }
        }
    }
}

// ---------------------------------------------------------------------------
// Kernel 3: exact top-5 per row from the 128 stored triples + per-block
// partial of the loss sum. NO single-address atomics (r4: removing the 2048
// same-address atomicAdds saved ~25-30us). Kernel 4 reduces the partials.
// ---------------------------------------------------------------------------
__global__ __launch_bounds__(256) void select_loss_kernel(const _Float16* __restrict__ xnh,
                                                          const float* __restrict__ M3,
                                                          float* __restrict__ partials) {
    const int wv = threadIdx.x >> 6, lane = threadIdx.x & 63;
    const int row = blockIdx.x * 4 + wv;
    const float* p = M3 + (size_t)row * NT64 * 3 + lane * 6;
    float a[3], b[3];
    a[0] = p[0]; a[1] = p[1]; a[2] = p[2];
    b[0] = p[3]; b[1] = p[4]; b[2] = p[5];

    float t[KNN];
    {
        float c[KNN] = { a[0], a[1], a[2], -2.f, -2.f };
        const float bb[KNN] = { b[0], b[1], b[2], -2.f, -2.f };
        merge5(c, bb);
        #pragma unroll
        for (int d = 1; d < 64; d <<= 1) {
            float o[KNN];
            #pragma unroll
            for (int k = 0; k < KNN; ++k) o[k] = __shfl_xor(c[k], d, 64);
            merge5(c, o);
        }
        #pragma unroll
        for (int k = 0; k < KNN; ++k) t[k] = c[k];
    }

    // flag tiles whose stored 3rd could hide a missed top-5 value
    const unsigned long long ba = __ballot(a[2] >= t[4]);
    const unsigned long long bb_ = __ballot(b[2] >= t[4]);
    if (ba | bb_) {
        // rebuild the pool top-5 excluding flagged tiles
        const bool fA = (ba >> lane) & 1ull, fB = (bb_ >> lane) & 1ull;
        float c[KNN] = { fA ? -2.f : a[0], fA ? -2.f : a[1], fA ? -2.f : a[2],
                         -2.f, -2.f };
        const float b5[KNN] = { fB ? -2.f : b[0], fB ? -2.f : b[1],
                                fB ? -2.f : b[2], -2.f, -2.f };
        merge5(c, b5);
        #pragma unroll
        for (int d = 1; d < 64; d <<= 1) {
            float o[KNN];
            #pragma unroll
            for (int k = 0; k < KNN; ++k) o[k] = __shfl_xor(c[k], d, 64);
            merge5(c, o);
        }
        #pragma unroll
        for (int k = 0; k < KNN; ++k) t[k] = c[k];

        // exactly recompute each flagged 64-col tile (whole wave, 1 col/lane)
        unsigned long long fl[2] = { ba, bb_ };
        #pragma unroll
        for (int h = 0; h < 2; ++h) {
            unsigned long long m = fl[h];
            while (m) {
                const int l = __ffsll((long long)m) - 1;
                m &= m - 1;
                const int jt2 = 2 * l + h;
                const int col = jt2 * 64 + lane;
                const _Float16* rp = xnh + (size_t)row * DIM;
                const _Float16* cp = xnh + (size_t)col * DIM;
                float d = 0.f;
                for (int k8 = 0; k8 < DIM / 8; ++k8) {
                    const f16x8 rv = *(const f16x8*)(rp + k8 * 8);
                    const f16x8 cv = *(const f16x8*)(cp + k8 * 8);
                    #pragma unroll
                    for (int e = 0; e < 8; ++e)
                        d += (float)rv[e] * (float)cv[e];
                }
                if (col == row) d = -2.f;
                float c2[KNN] = { d, -2.f, -2.f, -2.f, -2.f };
                #pragma unroll
                for (int dd = 1; dd < 64; dd <<= 1) {
                    float o[KNN];
                    #pragma unroll
                    for (int k = 0; k < KNN; ++k) o[k] = __shfl_xor(c2[k], dd, 64);
                    merge5(c2, o);
                }
                merge5(t, c2);
            }
        }
    }

    // loss term: unit vectors -> dist_k = sqrt(2 - 2*dot_k)
    float s = 0.f;
    #pragma unroll
    for (int k = 0; k < KNN; ++k) s += sqrtf(fmaxf(2.f - 2.f * t[k], 0.f));
    const float val = logf(s * (1.f / KNN) + EPSV);

    __shared__ float red[4];
    if (lane == 0) red[wv] = val;
    __syncthreads();
    if (threadIdx.x == 0)
        partials[blockIdx.x] = red[0] + red[1] + red[2] + red[3];
}

// ---------------------------------------------------------------------------
// Kernel 4: reduce the 2048 per-block partials -> loss. One block.
// ---------------------------------------------------------------------------
__global__ __launch_bounds__(256) void reduce_kernel(const float* __restrict__ partials,
                                                     float* __restrict__ out) {
    const int tid = threadIdx.x, lane = tid & 63, wv = tid >> 6;
    float s = 0.f;
    #pragma unroll
    for (int q = 0; q < NSEL / 256; ++q) s += partials[tid + q * 256];
    #pragma unroll
    for (int off = 1; off < 64; off <<= 1) s += __shfl_xor(s, off, 64);
    __shared__ float red[4];
    if (lane == 0) red[wv] = s;
    __syncthreads();
    if (tid == 0)
        *out = -(red[0] + red[1] + red[2] + red[3]) / (float)NROWS;
}

// ---------------------------------------------------------------------------
extern "C" void kernel_launch(void* const* d_in, const int* in_sizes, int n_in,
                              void* d_out, int out_size, void* d_ws, size_t ws_size,
                              hipStream_t stream) {
    const float* x = (const float*)d_in[0];
    float* out = (float*)d_out;
    char* ws = (char*)d_ws;

    _Float16* xnh = (_Float16*)ws;                                     // 8 MB
    float* M3 = (float*)(ws + (size_t)NROWS * DIM * sizeof(_Float16)); // 12.6 MB
    float* partials = M3 + (size_t)NROWS * NT64 * 3;                   // 8 KB

    norm_kernel<<<NROWS / 4, 256, 0, stream>>>(x, xnh);
    dots_top3_kernel<<<NWORK, 256, 0, stream>>>(xnh, M3);
    select_loss_kernel<<<NSEL, 256, 0, stream>>>(xnh, M3, partials);
    reduce_kernel<<<1, 256, 0, stream>>>(partials, out);
}